// Round 2
// baseline (5274.427 us; speedup 1.0000x reference)
//
#include <hip/hip_runtime.h>
#include <hip/hip_bf16.h>

// Dims
#define BB 32
#define TT 64
#define HH 512
#define EE 512
#define VV 32000

typedef float f32x4 __attribute__((ext_vector_type(4)));
typedef __bf16 bf16x8 __attribute__((ext_vector_type(8)));
typedef unsigned short u16x8 __attribute__((ext_vector_type(8)));

static __device__ __forceinline__ unsigned short f2bf(float f) {
  unsigned int u = __builtin_bit_cast(unsigned int, f);
  u += 0x7fffu + ((u >> 16) & 1u);   // RNE; inputs are finite
  return (unsigned short)(u >> 16);
}

// ---- fp32 -> bf16 bulk convert (8 elems/thread) ----
__global__ __launch_bounds__(256) void k_cvt_bf16(const float* __restrict__ in,
                                                  unsigned short* __restrict__ out,
                                                  int n8) {
  int tid = blockIdx.x * 256 + threadIdx.x;
  if (tid >= n8) return;
  int idx = tid * 8;
  float4 a = *(const float4*)(in + idx);
  float4 b = *(const float4*)(in + idx + 4);
  u16x8 o;
  o[0] = f2bf(a.x); o[1] = f2bf(a.y); o[2] = f2bf(a.z); o[3] = f2bf(a.w);
  o[4] = f2bf(b.x); o[5] = f2bf(b.y); o[6] = f2bf(b.z); o[7] = f2bf(b.w);
  *(u16x8*)(out + idx) = o;
}

// ---- embedding gather -> bf16, layout [t*B+b][E] ----
__global__ __launch_bounds__(256) void k_emb(const int* __restrict__ seq,
                                             const float* __restrict__ emb,
                                             unsigned short* __restrict__ out) {
  int tid = blockIdx.x * 256 + threadIdx.x;   // 2048*512/8 = 131072 threads
  int idx = tid * 8;
  int m = idx >> 9;          // t*32 + b
  int e0 = idx & 511;
  int t = m >> 5, b = m & 31;
  int s = seq[b * TT + t];
  const float* src = emb + (size_t)s * EE + e0;
  float4 a = *(const float4*)(src);
  float4 c = *(const float4*)(src + 4);
  u16x8 o;
  o[0] = f2bf(a.x); o[1] = f2bf(a.y); o[2] = f2bf(a.z); o[3] = f2bf(a.w);
  o[4] = f2bf(c.x); o[5] = f2bf(c.y); o[6] = f2bf(c.z); o[7] = f2bf(c.w);
  *(u16x8*)(out + m * EE + e0) = o;
}

// ---- W_eff = W_out[:, :H] @ W_in + W_out[:, H:]  (fp32, one-time) ----
__global__ __launch_bounds__(256) void k_weff(const float* __restrict__ W_out,
                                              const float* __restrict__ W_in,
                                              float* __restrict__ W_eff) {
  __shared__ float sa[16][17], sb[16][17];
  const int t16 = threadIdx.x & 15, ty = threadIdx.x >> 4;
  const int i = blockIdx.y * 16 + ty, m = blockIdx.x * 16 + t16;
  float acc = 0.f;
  for (int k0 = 0; k0 < HH; k0 += 16) {
    sa[ty][t16] = W_out[i * 1024 + k0 + t16];
    sb[ty][t16] = W_in[(k0 + ty) * HH + m];
    __syncthreads();
#pragma unroll
    for (int kk = 0; kk < 16; ++kk) acc += sa[ty][kk] * sb[kk][t16];
    __syncthreads();
  }
  W_eff[i * HH + m] = acc + W_out[i * 1024 + HH + m];
}

__global__ __launch_bounds__(256) void k_beff(const float* __restrict__ W_out,
                                              const float* __restrict__ b_in,
                                              const float* __restrict__ b_out,
                                              float* __restrict__ b_eff) {
  int i = blockIdx.x * 256 + threadIdx.x;
  if (i >= HH) return;
  float acc = b_out[i];
  for (int k = 0; k < HH; ++k) acc += W_out[i * 1024 + k] * b_in[k];
  b_eff[i] = acc;
}

// ---- bf16 MFMA GEMM: C[M][N] = A[M][K] * Bm[N][K]^T (+col biases, +row biases) ----
__global__ __launch_bounds__(256) void k_gemm(const unsigned short* __restrict__ A, int lda,
                                              const unsigned short* __restrict__ Bm, int ldb,
                                              float* __restrict__ C, int ldc,
                                              const float* __restrict__ bias1,
                                              const float* __restrict__ bias2,
                                              const float* __restrict__ biasR1,
                                              const float* __restrict__ biasR2,
                                              int K) {
  __shared__ unsigned short As[128][40];
  __shared__ unsigned short Bs[128][40];
  const int tx = threadIdx.x;
  const int lane = tx & 63, w = tx >> 6;
  const int wrow = (w >> 1) * 64, wcol = (w & 1) * 64;
  const int l15 = lane & 15, lk = lane >> 4;
  const int m0 = blockIdx.y * 128, n0 = blockIdx.x * 128;
  f32x4 acc[4][4] = {};
  for (int k0 = 0; k0 < K; k0 += 32) {
#pragma unroll
    for (int u = 0; u < 2; ++u) {
      int c = u * 256 + tx;               // 512 16B-chunks per matrix
      int row = c >> 2, cc = (c & 3) * 8;
      *(int4*)(&As[row][cc]) = *(const int4*)(A + (size_t)(m0 + row) * lda + k0 + cc);
      *(int4*)(&Bs[row][cc]) = *(const int4*)(Bm + (size_t)(n0 + row) * ldb + k0 + cc);
    }
    __syncthreads();
    bf16x8 av[4], bv[4];
#pragma unroll
    for (int mi = 0; mi < 4; ++mi)
      av[mi] = __builtin_bit_cast(bf16x8, *(const int4*)(&As[wrow + mi * 16 + l15][lk * 8]));
#pragma unroll
    for (int ni = 0; ni < 4; ++ni)
      bv[ni] = __builtin_bit_cast(bf16x8, *(const int4*)(&Bs[wcol + ni * 16 + l15][lk * 8]));
#pragma unroll
    for (int mi = 0; mi < 4; ++mi)
#pragma unroll
      for (int ni = 0; ni < 4; ++ni)
        acc[mi][ni] = __builtin_amdgcn_mfma_f32_16x16x32_bf16(av[mi], bv[ni], acc[mi][ni], 0, 0, 0);
    __syncthreads();
  }
#pragma unroll
  for (int mi = 0; mi < 4; ++mi) {
#pragma unroll
    for (int ni = 0; ni < 4; ++ni) {
      int row = m0 + wrow + mi * 16 + lk * 4;
      int col = n0 + wcol + ni * 16 + l15;
      float bb = 0.f;
      if (bias1) bb += bias1[col];
      if (bias2) bb += bias2[col];
#pragma unroll
      for (int q = 0; q < 4; ++q) {
        float bR = 0.f;
        if (biasR1) bR += biasR1[row + q];
        if (biasR2) bR += biasR2[row + q];
        C[(size_t)(row + q) * ldc + col] = acc[mi][ni][q] + bb + bR;
      }
    }
  }
}

// ---- two-level grid barrier (16 groups x 16 blocks), monotone phases ----
static __device__ __forceinline__ void gbar(unsigned* bar, int phase) {
  __syncthreads();
  if (threadIdx.x == 0) {
    const int g = blockIdx.x & 15;
    unsigned* grp = bar + 64 + g * 32;
    unsigned* mst = bar + 32;
    unsigned* gen = bar;
    __threadfence();
    unsigned v = __hip_atomic_fetch_add(grp, 1u, __ATOMIC_ACQ_REL, __HIP_MEMORY_SCOPE_AGENT);
    if (v == (unsigned)(phase * 16 + 15)) {
      unsigned m = __hip_atomic_fetch_add(mst, 1u, __ATOMIC_ACQ_REL, __HIP_MEMORY_SCOPE_AGENT);
      if (m == (unsigned)(phase * 16 + 15)) {
        __hip_atomic_store(gen, (unsigned)(phase + 1), __ATOMIC_RELEASE, __HIP_MEMORY_SCOPE_AGENT);
      }
    }
    while (__hip_atomic_load(gen, __ATOMIC_ACQUIRE, __HIP_MEMORY_SCOPE_AGENT) <= (unsigned)phase) {
      __builtin_amdgcn_s_sleep(2);
    }
  }
  __syncthreads();
  __threadfence();
}

// ---- persistent recurrence kernel: 256 blocks x 256 threads ----
// block bid owns output units i0=bid*2, i0+1. Weights live in LDS for all 64 steps.
__global__ __launch_bounds__(256) void k_recur(
    const float* __restrict__ xprojT,   // [2048][2048]: row j, col t*32+b (incl. b_ih+b_hh)
    const float* __restrict__ W_ih,     // [2048][1024] fp32
    const float* __restrict__ W_hh,     // [2048][512] fp32
    const float* __restrict__ W_eff,    // [512][512] fp32
    const float* __restrict__ b_eff,    // [512]
    const float* __restrict__ enc_h,    // [32][512]
    const float* __restrict__ enc_c,    // [32][512]
    float* __restrict__ h0,
    float* __restrict__ h1,
    float* __restrict__ outs_ext,       // [65][32][512]; slab 0 pre-zeroed
    unsigned* __restrict__ bar)
{
  __shared__ float4 sx4[32 * 65];      // x/h chunk staging + reduction scratch (33.3 KB)
  __shared__ float4 sw4[8][256];       // [W_f | W_h] rows for this block's 8 j-rows (32 KB)
  __shared__ float4 swe4[2][128];      // W_eff rows i0, i0+1 (4 KB)
  __shared__ float s_g[8][33];
  __shared__ float s_r[8][32];
  __shared__ float s_c[32][2];
  __shared__ float s_be[2];

  const int tx = threadIdx.x;
  const int bid = blockIdx.x;
  const int i0 = bid * 2;

  // one-time: stage gate weights [feed-half of W_ih | W_hh] for 8 j-rows
#pragma unroll
  for (int u = 0; u < 8; ++u) {
    int f4 = u * 256 + tx;
    int j = f4 >> 8, c4 = f4 & 255;
    int g = j >> 1, il = j & 1;
    int jg = g * 512 + i0 + il;
    const float* src = (c4 < 128)
        ? (W_ih + (size_t)jg * 1024 + 512 + c4 * 4)
        : (W_hh + (size_t)jg * 512 + (size_t)(c4 - 128) * 4);
    sw4[j][c4] = *(const float4*)src;
  }
  {
    int il = tx >> 7, c4 = tx & 127;
    swe4[il][c4] = *(const float4*)(W_eff + (size_t)(i0 + il) * 512 + c4 * 4);
  }
  if (tx < 64) {
    int il = tx >> 5, b = tx & 31;
    s_c[b][il] = enc_c[b * 512 + i0 + il];
  }
  if (tx < 2) s_be[tx] = b_eff[i0 + tx];

  const int p = tx & 7, s = tx >> 3;     // phase-1 tiling: b-group, k-slice
  const int jr = tx >> 5, br = tx & 31;  // reduce mapping
  const int b2 = tx & 31, q = tx >> 5;   // phase-2 mapping
  const int ilq = q >> 2, ks = q & 3;

  int phase = 0;
  for (int t = 0; t < 64; ++t) {
    const float* feed = outs_ext + (size_t)t * 16384;               // slab t
    const float* hin = (t == 0) ? enc_h : ((t & 1) ? h1 : h0);
    float* hout = (t & 1) ? h0 : h1;

    float acc[8][4];
#pragma unroll
    for (int j = 0; j < 8; ++j)
#pragma unroll
      for (int bi = 0; bi < 4; ++bi) acc[j][bi] = 0.f;

    // ---- phase 1: gates, K=1024 in 4 staged chunks of 256 ----
    for (int ch = 0; ch < 4; ++ch) {
      const float* src = (ch < 2) ? (feed + ch * 256) : (hin + (ch - 2) * 256);
      __syncthreads();
#pragma unroll
      for (int u = 0; u < 8; ++u) {
        int f4 = u * 256 + tx;
        int row = f4 >> 6, c4 = f4 & 63;
        sx4[row * 65 + c4] = *(const float4*)(src + (size_t)row * 512 + c4 * 4);
      }
      __syncthreads();
      float4 xv0[4], xv1[4];
#pragma unroll
      for (int bi = 0; bi < 4; ++bi) {
        int row = p * 4 + bi;
        xv0[bi] = sx4[row * 65 + s];
        xv1[bi] = sx4[row * 65 + s + 32];
      }
#pragma unroll
      for (int j = 0; j < 8; ++j) {
        float4 w0 = sw4[j][ch * 64 + s];
        float4 w1 = sw4[j][ch * 64 + s + 32];
#pragma unroll
        for (int bi = 0; bi < 4; ++bi) {
          acc[j][bi] += xv0[bi].x * w0.x + xv0[bi].y * w0.y + xv0[bi].z * w0.z + xv0[bi].w * w0.w
                      + xv1[bi].x * w1.x + xv1[bi].y * w1.y + xv1[bi].z * w1.z + xv1[bi].w * w1.w;
        }
      }
    }
    // reduce 32 k-slices
    __syncthreads();
    {
      float* red = (float*)sx4;
#pragma unroll
      for (int j = 0; j < 8; ++j) {
        float4 t4;
        t4.x = acc[j][0]; t4.y = acc[j][1]; t4.z = acc[j][2]; t4.w = acc[j][3];
        *(float4*)(red + s * 256 + j * 32 + p * 4) = t4;
      }
    }
    __syncthreads();
    {
      const float* red = (const float*)sx4;
      float sum = 0.f;
#pragma unroll
      for (int sl = 0; sl < 32; ++sl) sum += red[sl * 256 + jr * 32 + br];
      int g = jr >> 1, il = jr & 1;
      int jg = g * 512 + i0 + il;
      sum += xprojT[(size_t)jg * 2048 + t * 32 + br];
      s_g[jr][br] = sum;
    }
    __syncthreads();
    if (tx < 64) {
      int il = tx >> 5, b = tx & 31;
      float gi = s_g[il][b], gf = s_g[2 + il][b], gg = s_g[4 + il][b], go = s_g[6 + il][b];
      float cold = s_c[b][il];
      float si = 1.f / (1.f + __expf(-gi));
      float sf = 1.f / (1.f + __expf(-gf));
      float so = 1.f / (1.f + __expf(-go));
      float cn = sf * cold + si * tanhf(gg);
      s_c[b][il] = cn;
      hout[b * 512 + i0 + il] = so * tanhf(cn);
    }
    gbar(bar, phase++);   // h_t complete device-wide

    // ---- phase 2: feed_t slice = tanh(h_t @ W_eff[i0..i0+1]^T + b_eff) ----
    float part = 0.f;
    for (int ch = 0; ch < 2; ++ch) {
      __syncthreads();
#pragma unroll
      for (int u = 0; u < 8; ++u) {
        int f4 = u * 256 + tx;
        int row = f4 >> 6, c4 = f4 & 63;
        sx4[row * 65 + c4] = *(const float4*)(hout + (size_t)row * 512 + ch * 256 + c4 * 4);
      }
      __syncthreads();
#pragma unroll
      for (int kk = 0; kk < 16; ++kk) {
        float4 x4 = sx4[b2 * 65 + ks * 16 + kk];
        float4 w4 = swe4[ilq][ch * 64 + ks * 16 + kk];
        part += x4.x * w4.x + x4.y * w4.y + x4.z * w4.z + x4.w * w4.w;
      }
    }
    s_r[q][b2] = part;
    __syncthreads();
    if (tx < 64) {
      int il = tx >> 5, b = tx & 31;
      float v = s_r[il * 4 + 0][b] + s_r[il * 4 + 1][b] + s_r[il * 4 + 2][b] + s_r[il * 4 + 3][b]
              + s_be[il];
      outs_ext[(size_t)(t + 1) * 16384 + b * 512 + i0 + il] = tanhf(v);
    }
    gbar(bar, phase++);   // feed_t complete device-wide
  }
}

// ---- outs [T][B][H] fp32 -> A_bt [(b*T+t)][H] bf16 ----
__global__ __launch_bounds__(256) void k_tr(const float* __restrict__ outs,
                                            unsigned short* __restrict__ abt) {
  int tid = blockIdx.x * 256 + threadIdx.x;   // 131072 threads
  int idx = tid * 8;
  int m = idx >> 9;        // b*64 + t
  int h0 = idx & 511;
  int b = m >> 6, t = m & 63;
  const float* src = outs + (size_t)(t * 32 + b) * 512 + h0;
  float4 a = *(const float4*)(src);
  float4 c = *(const float4*)(src + 4);
  u16x8 o;
  o[0] = f2bf(a.x); o[1] = f2bf(a.y); o[2] = f2bf(a.z); o[3] = f2bf(a.w);
  o[4] = f2bf(c.x); o[5] = f2bf(c.y); o[6] = f2bf(c.z); o[7] = f2bf(c.w);
  *(u16x8*)(abt + m * 512 + h0) = o;
}

extern "C" void kernel_launch(void* const* d_in, const int* in_sizes, int n_in,
                              void* d_out, int out_size, void* d_ws, size_t ws_size,
                              hipStream_t stream) {
  const int*   seq      = (const int*)d_in[0];
  // d_in[1] = encoder_outputs: attention scores are dead code -> unused
  const float* enc_h    = (const float*)d_in[2];
  const float* enc_c    = (const float*)d_in[3];
  const float* emb      = (const float*)d_in[4];
  const float* W_ih     = (const float*)d_in[5];
  const float* b_ih     = (const float*)d_in[6];
  const float* W_hh     = (const float*)d_in[7];
  const float* b_hh     = (const float*)d_in[8];
  const float* W_inp    = (const float*)d_in[9];
  const float* b_inp    = (const float*)d_in[10];
  const float* W_outp   = (const float*)d_in[11];
  const float* b_outp   = (const float*)d_in[12];
  const float* W_final  = (const float*)d_in[13];
  const float* b_final  = (const float*)d_in[14];
  float* logits = (float*)d_out;

  char* ws = (char*)d_ws;
  size_t off = 0;
  auto alloc = [&](size_t bytes) {
    char* p = ws + off;
    off += (bytes + 255) & ~(size_t)255;
    return p;
  };
  unsigned short* wih_b  = (unsigned short*)alloc((size_t)2048 * 1024 * 2);
  unsigned short* wfin_b = (unsigned short*)alloc((size_t)VV * HH * 2);
  unsigned short* emb_b  = (unsigned short*)alloc((size_t)2048 * 512 * 2);
  float* xprojT = (float*)alloc((size_t)2048 * 2048 * 4);
  float* W_eff  = (float*)alloc((size_t)512 * 512 * 4);
  float* b_eff  = (float*)alloc((size_t)512 * 4);
  float* hbuf0  = (float*)alloc((size_t)32 * 512 * 4);
  float* hbuf1  = (float*)alloc((size_t)32 * 512 * 4);
  float* outs_e = (float*)alloc((size_t)65 * 32 * 512 * 4);
  unsigned short* abt = (unsigned short*)alloc((size_t)2048 * 512 * 2);
  unsigned* bar = (unsigned*)alloc(4096);

  // per-call init (graph-safe)
  hipMemsetAsync(bar, 0, 4096, stream);
  hipMemsetAsync(outs_e, 0, (size_t)32 * 512 * 4, stream);   // feed for t=0

  hipLaunchKernelGGL(k_cvt_bf16, dim3(1024), dim3(256), 0, stream, W_ih, wih_b, 2048 * 1024 / 8);
  hipLaunchKernelGGL(k_cvt_bf16, dim3(8000), dim3(256), 0, stream, W_final, wfin_b, VV * HH / 8);
  hipLaunchKernelGGL(k_emb, dim3(512), dim3(256), 0, stream, seq, emb, emb_b);
  hipLaunchKernelGGL(k_weff, dim3(32, 32), dim3(256), 0, stream, W_outp, W_inp, W_eff);
  hipLaunchKernelGGL(k_beff, dim3(2), dim3(256), 0, stream, W_outp, b_inp, b_outp, b_eff);

  // xprojT[j][t*32+b] = W_ih[:, :E] @ emb^T + (b_ih + b_hh) per-row
  hipLaunchKernelGGL(k_gemm, dim3(16, 16), dim3(256), 0, stream,
                     wih_b, 1024, emb_b, 512, xprojT, 2048,
                     (const float*)nullptr, (const float*)nullptr, b_ih, b_hh, 512);

  // persistent recurrence: all 64 steps, 2 grid barriers each
  hipLaunchKernelGGL(k_recur, dim3(256), dim3(256), 0, stream,
                     xprojT, W_ih, W_hh, W_eff, b_eff, enc_h, enc_c,
                     hbuf0, hbuf1, outs_e, bar);

  hipLaunchKernelGGL(k_tr, dim3(512), dim3(256), 0, stream, outs_e + 16384, abt);
  // logits[b*T+t][V] = A_bt @ W_final^T + b_final
  hipLaunchKernelGGL(k_gemm, dim3(250, 16), dim3(256), 0, stream,
                     abt, 512, wfin_b, 512, logits, 32000,
                     b_final, (const float*)nullptr, (const float*)nullptr, (const float*)nullptr, 512);
}

// Round 3
// 1980.417 us; speedup vs baseline: 2.6633x; 2.6633x over previous
//
#include <hip/hip_runtime.h>
#include <hip/hip_bf16.h>

// Dims
#define BB 32
#define TT 64
#define HH 512
#define EE 512
#define VV 32000

typedef float f32x4 __attribute__((ext_vector_type(4)));
typedef __bf16 bf16x8 __attribute__((ext_vector_type(8)));
typedef unsigned short u16x8 __attribute__((ext_vector_type(8)));

static __device__ __forceinline__ unsigned short f2bf(float f) {
  unsigned int u = __builtin_bit_cast(unsigned int, f);
  u += 0x7fffu + ((u >> 16) & 1u);   // RNE; inputs are finite
  return (unsigned short)(u >> 16);
}

// ---- fp32 -> bf16 bulk convert (8 elems/thread) ----
__global__ __launch_bounds__(256) void k_cvt_bf16(const float* __restrict__ in,
                                                  unsigned short* __restrict__ out,
                                                  int n8) {
  int tid = blockIdx.x * 256 + threadIdx.x;
  if (tid >= n8) return;
  int idx = tid * 8;
  float4 a = *(const float4*)(in + idx);
  float4 b = *(const float4*)(in + idx + 4);
  u16x8 o;
  o[0] = f2bf(a.x); o[1] = f2bf(a.y); o[2] = f2bf(a.z); o[3] = f2bf(a.w);
  o[4] = f2bf(b.x); o[5] = f2bf(b.y); o[6] = f2bf(b.z); o[7] = f2bf(b.w);
  *(u16x8*)(out + idx) = o;
}

// ---- embedding gather -> bf16, layout [t*B+b][E] ----
__global__ __launch_bounds__(256) void k_emb(const int* __restrict__ seq,
                                             const float* __restrict__ emb,
                                             unsigned short* __restrict__ out) {
  int tid = blockIdx.x * 256 + threadIdx.x;   // 2048*512/8 = 131072 threads
  int idx = tid * 8;
  int m = idx >> 9;          // t*32 + b
  int e0 = idx & 511;
  int t = m >> 5, b = m & 31;
  int s = seq[b * TT + t];
  const float* src = emb + (size_t)s * EE + e0;
  float4 a = *(const float4*)(src);
  float4 c = *(const float4*)(src + 4);
  u16x8 o;
  o[0] = f2bf(a.x); o[1] = f2bf(a.y); o[2] = f2bf(a.z); o[3] = f2bf(a.w);
  o[4] = f2bf(c.x); o[5] = f2bf(c.y); o[6] = f2bf(c.z); o[7] = f2bf(c.w);
  *(u16x8*)(out + m * EE + e0) = o;
}

// ---- W_eff = W_out[:, :H] @ W_in + W_out[:, H:]  (fp32, one-time) ----
__global__ __launch_bounds__(256) void k_weff(const float* __restrict__ W_out,
                                              const float* __restrict__ W_in,
                                              float* __restrict__ W_eff) {
  __shared__ float sa[16][17], sb[16][17];
  const int t16 = threadIdx.x & 15, ty = threadIdx.x >> 4;
  const int i = blockIdx.y * 16 + ty, m = blockIdx.x * 16 + t16;
  float acc = 0.f;
  for (int k0 = 0; k0 < HH; k0 += 16) {
    sa[ty][t16] = W_out[i * 1024 + k0 + t16];
    sb[ty][t16] = W_in[(k0 + ty) * HH + m];
    __syncthreads();
#pragma unroll
    for (int kk = 0; kk < 16; ++kk) acc += sa[ty][kk] * sb[kk][t16];
    __syncthreads();
  }
  W_eff[i * HH + m] = acc + W_out[i * 1024 + HH + m];
}

__global__ __launch_bounds__(256) void k_beff(const float* __restrict__ W_out,
                                              const float* __restrict__ b_in,
                                              const float* __restrict__ b_out,
                                              float* __restrict__ b_eff) {
  int i = blockIdx.x * 256 + threadIdx.x;
  if (i >= HH) return;
  float acc = b_out[i];
  for (int k = 0; k < HH; ++k) acc += W_out[i * 1024 + k] * b_in[k];
  b_eff[i] = acc;
}

// ---- bf16 MFMA GEMM: C[M][N] = A[M][K] * Bm[N][K]^T (+col biases, +row biases) ----
// 1-D grid (nb = n_panels*m_panels, nb%8==0), XCD-chunked bijective swizzle so each
// XCD works a contiguous N-range (B slice fits its private L2).
__global__ __launch_bounds__(256) void k_gemm(const unsigned short* __restrict__ A, int lda,
                                              const unsigned short* __restrict__ Bm, int ldb,
                                              float* __restrict__ C, int ldc,
                                              const float* __restrict__ bias1,
                                              const float* __restrict__ bias2,
                                              const float* __restrict__ biasR1,
                                              const float* __restrict__ biasR2,
                                              int K, int m_panels) {
  __shared__ unsigned short As[128][40];
  __shared__ unsigned short Bs[128][40];
  const int tx = threadIdx.x;
  const int lane = tx & 63, w = tx >> 6;
  const int wrow = (w >> 1) * 64, wcol = (w & 1) * 64;
  const int l15 = lane & 15, lk = lane >> 4;
  const int nb = gridDim.x;
  const int swz = (blockIdx.x & 7) * (nb >> 3) + (blockIdx.x >> 3);
  const int m0 = (swz % m_panels) * 128, n0 = (swz / m_panels) * 128;
  f32x4 acc[4][4] = {};
  for (int k0 = 0; k0 < K; k0 += 32) {
#pragma unroll
    for (int u = 0; u < 2; ++u) {
      int c = u * 256 + tx;               // 512 16B-chunks per matrix
      int row = c >> 2, cc = (c & 3) * 8;
      *(int4*)(&As[row][cc]) = *(const int4*)(A + (size_t)(m0 + row) * lda + k0 + cc);
      *(int4*)(&Bs[row][cc]) = *(const int4*)(Bm + (size_t)(n0 + row) * ldb + k0 + cc);
    }
    __syncthreads();
    bf16x8 av[4], bv[4];
#pragma unroll
    for (int mi = 0; mi < 4; ++mi)
      av[mi] = __builtin_bit_cast(bf16x8, *(const int4*)(&As[wrow + mi * 16 + l15][lk * 8]));
#pragma unroll
    for (int ni = 0; ni < 4; ++ni)
      bv[ni] = __builtin_bit_cast(bf16x8, *(const int4*)(&Bs[wcol + ni * 16 + l15][lk * 8]));
#pragma unroll
    for (int mi = 0; mi < 4; ++mi)
#pragma unroll
      for (int ni = 0; ni < 4; ++ni)
        acc[mi][ni] = __builtin_amdgcn_mfma_f32_16x16x32_bf16(av[mi], bv[ni], acc[mi][ni], 0, 0, 0);
    __syncthreads();
  }
#pragma unroll
  for (int mi = 0; mi < 4; ++mi) {
#pragma unroll
    for (int ni = 0; ni < 4; ++ni) {
      int row = m0 + wrow + mi * 16 + lk * 4;
      int col = n0 + wcol + ni * 16 + l15;
      float bb = 0.f;
      if (bias1) bb += bias1[col];
      if (bias2) bb += bias2[col];
#pragma unroll
      for (int q = 0; q < 4; ++q) {
        float bR = 0.f;
        if (biasR1) bR += biasR1[row + q];
        if (biasR2) bR += biasR2[row + q];
        C[(size_t)(row + q) * ldc + col] = acc[mi][ni][q] + bb + bR;
      }
    }
  }
}

// ---- flag-array grid barrier: parallel arrival stores, multi-thread master detect ----
// bar[0] = gensig; bar[32..32+nb) = per-block flags. All relaxed agent atomics;
// exactly one release fence per block (arrival) and one acquire fence (exit).
static __device__ __forceinline__ void gbar(unsigned* __restrict__ bar, unsigned gen) {
  __syncthreads();
  unsigned* gensig = bar;
  unsigned* flags = bar + 32;
  if (threadIdx.x == 0) {
    __builtin_amdgcn_fence(__ATOMIC_RELEASE, "agent");   // drain + make stores visible
    __hip_atomic_store(&flags[blockIdx.x], gen, __ATOMIC_RELAXED, __HIP_MEMORY_SCOPE_AGENT);
  }
  if (blockIdx.x == 0) {
    unsigned i = threadIdx.x;
    if (i < gridDim.x) {
      while (__hip_atomic_load(&flags[i], __ATOMIC_RELAXED, __HIP_MEMORY_SCOPE_AGENT) < gen)
        __builtin_amdgcn_s_sleep(1);
    }
    __syncthreads();
    if (threadIdx.x == 0)
      __hip_atomic_store(gensig, gen, __ATOMIC_RELAXED, __HIP_MEMORY_SCOPE_AGENT);
  }
  if (threadIdx.x == 0) {
    while (__hip_atomic_load(gensig, __ATOMIC_RELAXED, __HIP_MEMORY_SCOPE_AGENT) < gen)
      __builtin_amdgcn_s_sleep(1);
    __builtin_amdgcn_fence(__ATOMIC_ACQUIRE, "agent");   // invalidate L1/L2 before reading peers' data
  }
  __syncthreads();
}

// ---- persistent recurrence kernel: 256 blocks x 256 threads ----
// block bid owns output units i0=bid*2, i0+1. Gate weights live in LDS for all 64 steps;
// per-step x/h vectors are read directly from global (L2-resident after refill).
__global__ __launch_bounds__(256) void k_recur(
    const float* __restrict__ xprojT,   // [2048][2048]: row j, col t*32+b (incl. b_ih+b_hh)
    const float* __restrict__ W_ih,     // [2048][1024] fp32
    const float* __restrict__ W_hh,     // [2048][512] fp32
    const float* __restrict__ W_eff,    // [512][512] fp32
    const float* __restrict__ b_eff,    // [512]
    const float* __restrict__ enc_h,    // [32][512]
    const float* __restrict__ enc_c,    // [32][512]
    float* __restrict__ h0,
    float* __restrict__ h1,
    float* __restrict__ outs_ext,       // [65][32][512]; slab 0 pre-zeroed
    unsigned* __restrict__ bar)
{
  __shared__ float4 sw4[8][256];       // [W_f | W_h] rows for this block's 8 j-rows (32 KB)
  __shared__ float4 swe4[2][128];      // W_eff rows i0, i0+1 (4 KB)
  __shared__ float red[32 * 256];      // k-slice reduction scratch (32 KB)
  __shared__ float s_g[8][33];
  __shared__ float s_r[8][32];
  __shared__ float s_c[32][2];
  __shared__ float s_be[2];

  const int tx = threadIdx.x;
  const int bid = blockIdx.x;
  const int i0 = bid * 2;

  // one-time: stage gate weights [feed-half of W_ih | W_hh] for 8 j-rows
#pragma unroll
  for (int u = 0; u < 8; ++u) {
    int f4 = u * 256 + tx;
    int j = f4 >> 8, c4 = f4 & 255;
    int g = j >> 1, il = j & 1;
    int jg = g * 512 + i0 + il;
    const float* src = (c4 < 128)
        ? (W_ih + (size_t)jg * 1024 + 512 + c4 * 4)
        : (W_hh + (size_t)jg * 512 + (size_t)(c4 - 128) * 4);
    sw4[j][c4] = *(const float4*)src;
  }
  {
    int il = tx >> 7, c4 = tx & 127;
    swe4[il][c4] = *(const float4*)(W_eff + (size_t)(i0 + il) * 512 + c4 * 4);
  }
  if (tx < 64) {
    int il = tx >> 5, b = tx & 31;
    s_c[b][il] = enc_c[b * 512 + i0 + il];
  }
  if (tx < 2) s_be[tx] = b_eff[i0 + tx];

  const int p = tx & 7, s = tx >> 3;     // phase-1 tiling: batch-group, k-slice
  const int jr = tx >> 5, br = tx & 31;  // reduce mapping
  const int b2 = tx & 31, q = tx >> 5;   // phase-2 mapping
  const int ilq = q >> 2, ks = q & 3;

  unsigned gen = 1;
  for (int t = 0; t < 64; ++t) {
    const float* feed = outs_ext + (size_t)t * 16384;               // slab t
    const float* hin = (t == 0) ? enc_h : ((t & 1) ? h1 : h0);
    float* hout = (t & 1) ? h0 : h1;

    float acc[8][4];
#pragma unroll
    for (int j = 0; j < 8; ++j)
#pragma unroll
      for (int bi = 0; bi < 4; ++bi) acc[j][bi] = 0.f;

    // ---- phase 1: gates, K=1024, x/h read straight from global ----
    for (int ch = 0; ch < 4; ++ch) {
      const float* src = (ch < 2) ? (feed + ch * 256) : (hin + (ch - 2) * 256);
      float4 xv0[4], xv1[4];
#pragma unroll
      for (int bi = 0; bi < 4; ++bi) {
        const float* rowp = src + (size_t)(p * 4 + bi) * 512;
        xv0[bi] = *(const float4*)(rowp + s * 4);
        xv1[bi] = *(const float4*)(rowp + (s + 32) * 4);
      }
#pragma unroll
      for (int j = 0; j < 8; ++j) {
        float4 w0 = sw4[j][ch * 64 + s];
        float4 w1 = sw4[j][ch * 64 + s + 32];
#pragma unroll
        for (int bi = 0; bi < 4; ++bi) {
          acc[j][bi] += xv0[bi].x * w0.x + xv0[bi].y * w0.y + xv0[bi].z * w0.z + xv0[bi].w * w0.w
                      + xv1[bi].x * w1.x + xv1[bi].y * w1.y + xv1[bi].z * w1.z + xv1[bi].w * w1.w;
        }
      }
    }
    // reduce 32 k-slices
#pragma unroll
    for (int j = 0; j < 8; ++j) {
      float4 t4;
      t4.x = acc[j][0]; t4.y = acc[j][1]; t4.z = acc[j][2]; t4.w = acc[j][3];
      *(float4*)(red + s * 256 + j * 32 + p * 4) = t4;
    }
    __syncthreads();
    {
      float sum = 0.f;
#pragma unroll
      for (int sl = 0; sl < 32; ++sl) sum += red[sl * 256 + jr * 32 + br];
      int g = jr >> 1, il = jr & 1;
      int jg = g * 512 + i0 + il;
      sum += xprojT[(size_t)jg * 2048 + t * 32 + br];
      s_g[jr][br] = sum;
    }
    __syncthreads();
    if (tx < 64) {
      int il = tx >> 5, b = tx & 31;
      float gi = s_g[il][b], gf = s_g[2 + il][b], gg = s_g[4 + il][b], go = s_g[6 + il][b];
      float cold = s_c[b][il];
      float si = 1.f / (1.f + __expf(-gi));
      float sf = 1.f / (1.f + __expf(-gf));
      float so = 1.f / (1.f + __expf(-go));
      float cn = sf * cold + si * tanhf(gg);
      s_c[b][il] = cn;
      hout[b * 512 + i0 + il] = so * tanhf(cn);
    }
    gbar(bar, gen++);   // h_t complete device-wide

    // ---- phase 2: feed_t slice = tanh(h_t @ W_eff[i0..i0+1]^T + b_eff) ----
    float part = 0.f;
#pragma unroll
    for (int ch = 0; ch < 2; ++ch) {
      const float* rowp = hout + (size_t)b2 * 512 + ch * 256;
#pragma unroll
      for (int kk = 0; kk < 16; ++kk) {
        float4 x4 = *(const float4*)(rowp + (ks * 16 + kk) * 4);
        float4 w4 = swe4[ilq][ch * 64 + ks * 16 + kk];
        part += x4.x * w4.x + x4.y * w4.y + x4.z * w4.z + x4.w * w4.w;
      }
    }
    s_r[q][b2] = part;
    __syncthreads();
    if (tx < 64) {
      int il = tx >> 5, b = tx & 31;
      float v = s_r[il * 4 + 0][b] + s_r[il * 4 + 1][b] + s_r[il * 4 + 2][b] + s_r[il * 4 + 3][b]
              + s_be[il];
      outs_ext[(size_t)(t + 1) * 16384 + b * 512 + i0 + il] = tanhf(v);
    }
    gbar(bar, gen++);   // feed_t complete device-wide
  }
}

// ---- outs [T][B][H] fp32 -> A_bt [(b*T+t)][H] bf16 ----
__global__ __launch_bounds__(256) void k_tr(const float* __restrict__ outs,
                                            unsigned short* __restrict__ abt) {
  int tid = blockIdx.x * 256 + threadIdx.x;   // 131072 threads
  int idx = tid * 8;
  int m = idx >> 9;        // b*64 + t
  int h0 = idx & 511;
  int b = m >> 6, t = m & 63;
  const float* src = outs + (size_t)(t * 32 + b) * 512 + h0;
  float4 a = *(const float4*)(src);
  float4 c = *(const float4*)(src + 4);
  u16x8 o;
  o[0] = f2bf(a.x); o[1] = f2bf(a.y); o[2] = f2bf(a.z); o[3] = f2bf(a.w);
  o[4] = f2bf(c.x); o[5] = f2bf(c.y); o[6] = f2bf(c.z); o[7] = f2bf(c.w);
  *(u16x8*)(abt + m * 512 + h0) = o;
}

extern "C" void kernel_launch(void* const* d_in, const int* in_sizes, int n_in,
                              void* d_out, int out_size, void* d_ws, size_t ws_size,
                              hipStream_t stream) {
  const int*   seq      = (const int*)d_in[0];
  // d_in[1] = encoder_outputs: attention scores are dead code -> unused
  const float* enc_h    = (const float*)d_in[2];
  const float* enc_c    = (const float*)d_in[3];
  const float* emb      = (const float*)d_in[4];
  const float* W_ih     = (const float*)d_in[5];
  const float* b_ih     = (const float*)d_in[6];
  const float* W_hh     = (const float*)d_in[7];
  const float* b_hh     = (const float*)d_in[8];
  const float* W_inp    = (const float*)d_in[9];
  const float* b_inp    = (const float*)d_in[10];
  const float* W_outp   = (const float*)d_in[11];
  const float* b_outp   = (const float*)d_in[12];
  const float* W_final  = (const float*)d_in[13];
  const float* b_final  = (const float*)d_in[14];
  float* logits = (float*)d_out;

  char* ws = (char*)d_ws;
  size_t off = 0;
  auto alloc = [&](size_t bytes) {
    char* p = ws + off;
    off += (bytes + 255) & ~(size_t)255;
    return p;
  };
  unsigned short* wih_b  = (unsigned short*)alloc((size_t)2048 * 1024 * 2);
  unsigned short* wfin_b = (unsigned short*)alloc((size_t)VV * HH * 2);
  unsigned short* emb_b  = (unsigned short*)alloc((size_t)2048 * 512 * 2);
  float* xprojT = (float*)alloc((size_t)2048 * 2048 * 4);
  float* W_eff  = (float*)alloc((size_t)512 * 512 * 4);
  float* b_eff  = (float*)alloc((size_t)512 * 4);
  float* hbuf0  = (float*)alloc((size_t)32 * 512 * 4);
  float* hbuf1  = (float*)alloc((size_t)32 * 512 * 4);
  float* outs_e = (float*)alloc((size_t)65 * 32 * 512 * 4);
  unsigned short* abt = (unsigned short*)alloc((size_t)2048 * 512 * 2);
  unsigned* bar = (unsigned*)alloc(4096);

  // per-call init (graph-safe)
  hipMemsetAsync(bar, 0, 4096, stream);
  hipMemsetAsync(outs_e, 0, (size_t)32 * 512 * 4, stream);   // feed for t=0

  hipLaunchKernelGGL(k_cvt_bf16, dim3(1024), dim3(256), 0, stream, W_ih, wih_b, 2048 * 1024 / 8);
  hipLaunchKernelGGL(k_cvt_bf16, dim3(8000), dim3(256), 0, stream, W_final, wfin_b, VV * HH / 8);
  hipLaunchKernelGGL(k_emb, dim3(512), dim3(256), 0, stream, seq, emb, emb_b);
  hipLaunchKernelGGL(k_weff, dim3(32, 32), dim3(256), 0, stream, W_outp, W_inp, W_eff);
  hipLaunchKernelGGL(k_beff, dim3(2), dim3(256), 0, stream, W_outp, b_inp, b_outp, b_eff);

  // xprojT[j][t*32+b] = W_ih[:, :E] @ emb^T + (b_ih + b_hh) per-row
  hipLaunchKernelGGL(k_gemm, dim3(256), dim3(256), 0, stream,
                     wih_b, 1024, emb_b, 512, xprojT, 2048,
                     (const float*)nullptr, (const float*)nullptr, b_ih, b_hh, 512, 16);

  // persistent recurrence: all 64 steps, 2 flag-barriers each
  hipLaunchKernelGGL(k_recur, dim3(256), dim3(256), 0, stream,
                     xprojT, W_ih, W_hh, W_eff, b_eff, enc_h, enc_c,
                     hbuf0, hbuf1, outs_e, bar);

  hipLaunchKernelGGL(k_tr, dim3(512), dim3(256), 0, stream, outs_e + 16384, abt);
  // logits[b*T+t][V] = A_bt @ W_final^T + b_final
  hipLaunchKernelGGL(k_gemm, dim3(4000), dim3(256), 0, stream,
                     abt, 512, wfin_b, 512, logits, 32000,
                     b_final, (const float*)nullptr, (const float*)nullptr, (const float*)nullptr, 512, 16);
}

// Round 4
// 1115.019 us; speedup vs baseline: 4.7303x; 1.7761x over previous
//
#include <hip/hip_runtime.h>
#include <hip/hip_bf16.h>

// Dims
#define BB 32
#define TT 64
#define HH 512
#define EE 512
#define VV 32000

typedef float f32x4 __attribute__((ext_vector_type(4)));
typedef __bf16 bf16x8 __attribute__((ext_vector_type(8)));
typedef unsigned short u16x8 __attribute__((ext_vector_type(8)));

static __device__ __forceinline__ unsigned short f2bf(float f) {
  unsigned int u = __builtin_bit_cast(unsigned int, f);
  u += 0x7fffu + ((u >> 16) & 1u);   // RNE; inputs are finite
  return (unsigned short)(u >> 16);
}

// ---- fp32 -> bf16 bulk convert (8 elems/thread) ----
__global__ __launch_bounds__(256) void k_cvt_bf16(const float* __restrict__ in,
                                                  unsigned short* __restrict__ out,
                                                  int n8) {
  int tid = blockIdx.x * 256 + threadIdx.x;
  if (tid >= n8) return;
  int idx = tid * 8;
  float4 a = *(const float4*)(in + idx);
  float4 b = *(const float4*)(in + idx + 4);
  u16x8 o;
  o[0] = f2bf(a.x); o[1] = f2bf(a.y); o[2] = f2bf(a.z); o[3] = f2bf(a.w);
  o[4] = f2bf(b.x); o[5] = f2bf(b.y); o[6] = f2bf(b.z); o[7] = f2bf(b.w);
  *(u16x8*)(out + idx) = o;
}

// ---- embedding gather -> bf16, layout [t*B+b][E] ----
__global__ __launch_bounds__(256) void k_emb(const int* __restrict__ seq,
                                             const float* __restrict__ emb,
                                             unsigned short* __restrict__ out) {
  int tid = blockIdx.x * 256 + threadIdx.x;   // 2048*512/8 = 131072 threads
  int idx = tid * 8;
  int m = idx >> 9;          // t*32 + b
  int e0 = idx & 511;
  int t = m >> 5, b = m & 31;
  int s = seq[b * TT + t];
  const float* src = emb + (size_t)s * EE + e0;
  float4 a = *(const float4*)(src);
  float4 c = *(const float4*)(src + 4);
  u16x8 o;
  o[0] = f2bf(a.x); o[1] = f2bf(a.y); o[2] = f2bf(a.z); o[3] = f2bf(a.w);
  o[4] = f2bf(c.x); o[5] = f2bf(c.y); o[6] = f2bf(c.z); o[7] = f2bf(c.w);
  *(u16x8*)(out + m * EE + e0) = o;
}

// ---- W_eff = W_out[:, :H] @ W_in + W_out[:, H:]  (fp32, one-time) ----
__global__ __launch_bounds__(256) void k_weff(const float* __restrict__ W_out,
                                              const float* __restrict__ W_in,
                                              float* __restrict__ W_eff) {
  __shared__ float sa[16][17], sb[16][17];
  const int t16 = threadIdx.x & 15, ty = threadIdx.x >> 4;
  const int i = blockIdx.y * 16 + ty, m = blockIdx.x * 16 + t16;
  float acc = 0.f;
  for (int k0 = 0; k0 < HH; k0 += 16) {
    sa[ty][t16] = W_out[i * 1024 + k0 + t16];
    sb[ty][t16] = W_in[(k0 + ty) * HH + m];
    __syncthreads();
#pragma unroll
    for (int kk = 0; kk < 16; ++kk) acc += sa[ty][kk] * sb[kk][t16];
    __syncthreads();
  }
  W_eff[i * HH + m] = acc + W_out[i * 1024 + HH + m];
}

__global__ __launch_bounds__(256) void k_beff(const float* __restrict__ W_out,
                                              const float* __restrict__ b_in,
                                              const float* __restrict__ b_out,
                                              float* __restrict__ b_eff) {
  int i = blockIdx.x * 256 + threadIdx.x;
  if (i >= HH) return;
  float acc = b_out[i];
  for (int k = 0; k < HH; ++k) acc += W_out[i * 1024 + k] * b_in[k];
  b_eff[i] = acc;
}

// ---- bf16 MFMA GEMM: C[M][N] = A[M][K] * Bm[N][K]^T (+col biases, +row biases) ----
// 1-D grid, XCD-chunked bijective swizzle for L2 locality.
__global__ __launch_bounds__(256) void k_gemm(const unsigned short* __restrict__ A, int lda,
                                              const unsigned short* __restrict__ Bm, int ldb,
                                              float* __restrict__ C, int ldc,
                                              const float* __restrict__ bias1,
                                              const float* __restrict__ bias2,
                                              const float* __restrict__ biasR1,
                                              const float* __restrict__ biasR2,
                                              int K, int m_panels) {
  __shared__ unsigned short As[128][40];
  __shared__ unsigned short Bs[128][40];
  const int tx = threadIdx.x;
  const int lane = tx & 63, w = tx >> 6;
  const int wrow = (w >> 1) * 64, wcol = (w & 1) * 64;
  const int l15 = lane & 15, lk = lane >> 4;
  const int nb = gridDim.x;
  const int swz = (blockIdx.x & 7) * (nb >> 3) + (blockIdx.x >> 3);
  const int m0 = (swz % m_panels) * 128, n0 = (swz / m_panels) * 128;
  f32x4 acc[4][4] = {};
  for (int k0 = 0; k0 < K; k0 += 32) {
#pragma unroll
    for (int u = 0; u < 2; ++u) {
      int c = u * 256 + tx;               // 512 16B-chunks per matrix
      int row = c >> 2, cc = (c & 3) * 8;
      *(int4*)(&As[row][cc]) = *(const int4*)(A + (size_t)(m0 + row) * lda + k0 + cc);
      *(int4*)(&Bs[row][cc]) = *(const int4*)(Bm + (size_t)(n0 + row) * ldb + k0 + cc);
    }
    __syncthreads();
    bf16x8 av[4], bv[4];
#pragma unroll
    for (int mi = 0; mi < 4; ++mi)
      av[mi] = __builtin_bit_cast(bf16x8, *(const int4*)(&As[wrow + mi * 16 + l15][lk * 8]));
#pragma unroll
    for (int ni = 0; ni < 4; ++ni)
      bv[ni] = __builtin_bit_cast(bf16x8, *(const int4*)(&Bs[wcol + ni * 16 + l15][lk * 8]));
#pragma unroll
    for (int mi = 0; mi < 4; ++mi)
#pragma unroll
      for (int ni = 0; ni < 4; ++ni)
        acc[mi][ni] = __builtin_amdgcn_mfma_f32_16x16x32_bf16(av[mi], bv[ni], acc[mi][ni], 0, 0, 0);
    __syncthreads();
  }
#pragma unroll
  for (int mi = 0; mi < 4; ++mi) {
#pragma unroll
    for (int ni = 0; ni < 4; ++ni) {
      int row = m0 + wrow + mi * 16 + lk * 4;
      int col = n0 + wcol + ni * 16 + l15;
      float bb = 0.f;
      if (bias1) bb += bias1[col];
      if (bias2) bb += bias2[col];
#pragma unroll
      for (int q = 0; q < 4; ++q) {
        float bR = 0.f;
        if (biasR1) bR += biasR1[row + q];
        if (biasR2) bR += biasR2[row + q];
        C[(size_t)(row + q) * ldc + col] = acc[mi][ni][q] + bb + bR;
      }
    }
  }
}

// ---- fence-free grid barrier ----
// Shared data is published via agent-scope relaxed atomic stores (write-through to
// MALL; no dirty L2 lines), and every cross-block read targets a never-before-cached
// slab -> plain loads are always fresh. So the barrier needs NO cache maintenance:
// vmcnt drain (done by __syncthreads) + relaxed flag protocol only.
// bar[0]=gensig; bar[64..64+nb)=per-block flags.
static __device__ __forceinline__ void gbar(unsigned* __restrict__ bar, unsigned gen) {
  __syncthreads();   // all waves drain their vmem (stores at coherence point) + block sync
  unsigned* gensig = bar;
  unsigned* flags = bar + 64;
  if (threadIdx.x == 0) {
    asm volatile("s_waitcnt vmcnt(0)" ::: "memory");
    __hip_atomic_store(&flags[blockIdx.x], gen, __ATOMIC_RELAXED, __HIP_MEMORY_SCOPE_AGENT);
  }
  if (blockIdx.x == 0) {
    if ((int)threadIdx.x < (int)gridDim.x) {
      while (__hip_atomic_load(&flags[threadIdx.x], __ATOMIC_RELAXED, __HIP_MEMORY_SCOPE_AGENT) < gen)
        __builtin_amdgcn_s_sleep(1);
    }
    __syncthreads();
    if (threadIdx.x == 0)
      __hip_atomic_store(gensig, gen, __ATOMIC_RELAXED, __HIP_MEMORY_SCOPE_AGENT);
  }
  if (threadIdx.x == 0) {
    while (__hip_atomic_load(gensig, __ATOMIC_RELAXED, __HIP_MEMORY_SCOPE_AGENT) < gen)
      __builtin_amdgcn_s_sleep(1);
  }
  __syncthreads();
  asm volatile("" ::: "memory");   // compile-time barrier: keep data loads below the spin
}

// ---- persistent recurrence kernel: 256 blocks x 256 threads ----
// block bid owns output units i0=bid*2, i0+1. Gate weights live in LDS for all 64 steps.
// h and feed both live in step-unique slabs so plain cached loads are never stale.
__global__ __launch_bounds__(256) void k_recur(
    const float* __restrict__ xprojT,   // [2048][2048]: row j, col t*32+b (incl. b_ih+b_hh)
    const float* __restrict__ W_ih,     // [2048][1024] fp32
    const float* __restrict__ W_hh,     // [2048][512] fp32
    const float* __restrict__ W_eff,    // [512][512] fp32
    const float* __restrict__ b_eff,    // [512]
    const float* __restrict__ enc_c,    // [32][512]
    float* __restrict__ h_ext,          // [65][32][512]; slab 0 = enc_h (pre-copied)
    float* __restrict__ outs_ext,       // [65][32][512]; slab 0 pre-zeroed
    unsigned* __restrict__ bar)
{
  __shared__ float4 sw4[8][256];       // [W_f | W_h] rows for this block's 8 j-rows (32 KB)
  __shared__ float4 swe4[2][128];      // W_eff rows i0, i0+1 (4 KB)
  __shared__ float red[32 * 256];      // k-slice reduction scratch (32 KB)
  __shared__ float s_g[8][33];
  __shared__ float s_r[8][32];
  __shared__ float s_c[32][2];
  __shared__ float s_be[2];

  const int tx = threadIdx.x;
  const int bid = blockIdx.x;
  const int i0 = bid * 2;

  // one-time: stage gate weights [feed-half of W_ih | W_hh] for 8 j-rows
#pragma unroll
  for (int u = 0; u < 8; ++u) {
    int f4 = u * 256 + tx;
    int j = f4 >> 8, c4 = f4 & 255;
    int g = j >> 1, il = j & 1;
    int jg = g * 512 + i0 + il;
    const float* src = (c4 < 128)
        ? (W_ih + (size_t)jg * 1024 + 512 + c4 * 4)
        : (W_hh + (size_t)jg * 512 + (size_t)(c4 - 128) * 4);
    sw4[j][c4] = *(const float4*)src;
  }
  {
    int il = tx >> 7, c4 = tx & 127;
    swe4[il][c4] = *(const float4*)(W_eff + (size_t)(i0 + il) * 512 + c4 * 4);
  }
  if (tx < 64) {
    int il = tx >> 5, b = tx & 31;
    s_c[b][il] = enc_c[b * 512 + i0 + il];
  }
  if (tx < 2) s_be[tx] = b_eff[i0 + tx];

  const int p = tx & 7, s = tx >> 3;     // phase-1 tiling: batch-group, k-slice
  const int jr = tx >> 5, br = tx & 31;  // reduce mapping
  const int b2 = tx & 31, q = tx >> 5;   // phase-2 mapping
  const int ilq = q >> 2, ks = q & 3;

  unsigned gen = 1;
  for (int t = 0; t < 64; ++t) {
    const float* feed = outs_ext + (size_t)t * 16384;        // slab t
    const float* hin  = h_ext + (size_t)t * 16384;           // slab t
    float* hout       = h_ext + (size_t)(t + 1) * 16384;     // slab t+1

    float acc[8][4];
#pragma unroll
    for (int j = 0; j < 8; ++j)
#pragma unroll
      for (int bi = 0; bi < 4; ++bi) acc[j][bi] = 0.f;

    // ---- phase 1: gates, K=1024, x/h read straight from global (fresh slabs) ----
    for (int ch = 0; ch < 4; ++ch) {
      const float* src = (ch < 2) ? (feed + ch * 256) : (hin + (ch - 2) * 256);
      float4 xv0[4], xv1[4];
#pragma unroll
      for (int bi = 0; bi < 4; ++bi) {
        const float* rowp = src + (size_t)(p * 4 + bi) * 512;
        xv0[bi] = *(const float4*)(rowp + s * 4);
        xv1[bi] = *(const float4*)(rowp + (s + 32) * 4);
      }
#pragma unroll
      for (int j = 0; j < 8; ++j) {
        float4 w0 = sw4[j][ch * 64 + s];
        float4 w1 = sw4[j][ch * 64 + s + 32];
#pragma unroll
        for (int bi = 0; bi < 4; ++bi) {
          acc[j][bi] += xv0[bi].x * w0.x + xv0[bi].y * w0.y + xv0[bi].z * w0.z + xv0[bi].w * w0.w
                      + xv1[bi].x * w1.x + xv1[bi].y * w1.y + xv1[bi].z * w1.z + xv1[bi].w * w1.w;
        }
      }
    }
    // reduce 32 k-slices
#pragma unroll
    for (int j = 0; j < 8; ++j) {
      float4 t4;
      t4.x = acc[j][0]; t4.y = acc[j][1]; t4.z = acc[j][2]; t4.w = acc[j][3];
      *(float4*)(red + s * 256 + j * 32 + p * 4) = t4;
    }
    __syncthreads();
    {
      float sum = 0.f;
#pragma unroll
      for (int sl = 0; sl < 32; ++sl) sum += red[sl * 256 + jr * 32 + br];
      int g = jr >> 1, il = jr & 1;
      int jg = g * 512 + i0 + il;
      sum += xprojT[(size_t)jg * 2048 + t * 32 + br];
      s_g[jr][br] = sum;
    }
    __syncthreads();
    if (tx < 64) {
      int il = tx >> 5, b = tx & 31;
      float gi = s_g[il][b], gf = s_g[2 + il][b], gg = s_g[4 + il][b], go = s_g[6 + il][b];
      float cold = s_c[b][il];
      float si = 1.f / (1.f + __expf(-gi));
      float sf = 1.f / (1.f + __expf(-gf));
      float so = 1.f / (1.f + __expf(-go));
      float cn = sf * cold + si * tanhf(gg);
      s_c[b][il] = cn;
      __hip_atomic_store(&hout[b * 512 + i0 + il], so * tanhf(cn),
                         __ATOMIC_RELAXED, __HIP_MEMORY_SCOPE_AGENT);
    }
    gbar(bar, gen++);   // h_t complete device-wide

    // ---- phase 2: feed_t slice = tanh(h_t @ W_eff[i0..i0+1]^T + b_eff) ----
    float part = 0.f;
#pragma unroll
    for (int ch = 0; ch < 2; ++ch) {
      const float* rowp = hout + (size_t)b2 * 512 + ch * 256;
#pragma unroll
      for (int kk = 0; kk < 16; ++kk) {
        float4 x4 = *(const float4*)(rowp + (ks * 16 + kk) * 4);
        float4 w4 = swe4[ilq][ch * 64 + ks * 16 + kk];
        part += x4.x * w4.x + x4.y * w4.y + x4.z * w4.z + x4.w * w4.w;
      }
    }
    s_r[q][b2] = part;
    __syncthreads();
    if (tx < 64) {
      int il = tx >> 5, b = tx & 31;
      float v = s_r[il * 4 + 0][b] + s_r[il * 4 + 1][b] + s_r[il * 4 + 2][b] + s_r[il * 4 + 3][b]
              + s_be[il];
      __hip_atomic_store(&outs_ext[(size_t)(t + 1) * 16384 + b * 512 + i0 + il], tanhf(v),
                         __ATOMIC_RELAXED, __HIP_MEMORY_SCOPE_AGENT);
    }
    gbar(bar, gen++);   // feed_t complete device-wide
  }
}

// ---- outs [T][B][H] fp32 -> A_bt [(b*T+t)][H] bf16 ----
__global__ __launch_bounds__(256) void k_tr(const float* __restrict__ outs,
                                            unsigned short* __restrict__ abt) {
  int tid = blockIdx.x * 256 + threadIdx.x;   // 131072 threads
  int idx = tid * 8;
  int m = idx >> 9;        // b*64 + t
  int h0 = idx & 511;
  int b = m >> 6, t = m & 63;
  const float* src = outs + (size_t)(t * 32 + b) * 512 + h0;
  float4 a = *(const float4*)(src);
  float4 c = *(const float4*)(src + 4);
  u16x8 o;
  o[0] = f2bf(a.x); o[1] = f2bf(a.y); o[2] = f2bf(a.z); o[3] = f2bf(a.w);
  o[4] = f2bf(c.x); o[5] = f2bf(c.y); o[6] = f2bf(c.z); o[7] = f2bf(c.w);
  *(u16x8*)(abt + m * 512 + h0) = o;
}

extern "C" void kernel_launch(void* const* d_in, const int* in_sizes, int n_in,
                              void* d_out, int out_size, void* d_ws, size_t ws_size,
                              hipStream_t stream) {
  const int*   seq      = (const int*)d_in[0];
  // d_in[1] = encoder_outputs: attention scores are dead code -> unused
  const float* enc_h    = (const float*)d_in[2];
  const float* enc_c    = (const float*)d_in[3];
  const float* emb      = (const float*)d_in[4];
  const float* W_ih     = (const float*)d_in[5];
  const float* b_ih     = (const float*)d_in[6];
  const float* W_hh     = (const float*)d_in[7];
  const float* b_hh     = (const float*)d_in[8];
  const float* W_inp    = (const float*)d_in[9];
  const float* b_inp    = (const float*)d_in[10];
  const float* W_outp   = (const float*)d_in[11];
  const float* b_outp   = (const float*)d_in[12];
  const float* W_final  = (const float*)d_in[13];
  const float* b_final  = (const float*)d_in[14];
  float* logits = (float*)d_out;

  char* ws = (char*)d_ws;
  size_t off = 0;
  auto alloc = [&](size_t bytes) {
    char* p = ws + off;
    off += (bytes + 255) & ~(size_t)255;
    return p;
  };
  unsigned short* wih_b  = (unsigned short*)alloc((size_t)2048 * 1024 * 2);
  unsigned short* wfin_b = (unsigned short*)alloc((size_t)VV * HH * 2);
  unsigned short* emb_b  = (unsigned short*)alloc((size_t)2048 * 512 * 2);
  float* xprojT = (float*)alloc((size_t)2048 * 2048 * 4);
  float* W_eff  = (float*)alloc((size_t)512 * 512 * 4);
  float* b_eff  = (float*)alloc((size_t)512 * 4);
  float* h_ext  = (float*)alloc((size_t)65 * 32 * 512 * 4);
  float* outs_e = (float*)alloc((size_t)65 * 32 * 512 * 4);
  unsigned short* abt = (unsigned short*)alloc((size_t)2048 * 512 * 2);
  unsigned* bar = (unsigned*)alloc(4096);

  // per-call init (graph-safe)
  hipMemsetAsync(bar, 0, 4096, stream);
  hipMemsetAsync(outs_e, 0, (size_t)32 * 512 * 4, stream);   // feed for t=0
  hipMemcpyAsync(h_ext, enc_h, (size_t)32 * 512 * 4, hipMemcpyDeviceToDevice, stream);

  hipLaunchKernelGGL(k_cvt_bf16, dim3(1024), dim3(256), 0, stream, W_ih, wih_b, 2048 * 1024 / 8);
  hipLaunchKernelGGL(k_cvt_bf16, dim3(8000), dim3(256), 0, stream, W_final, wfin_b, VV * HH / 8);
  hipLaunchKernelGGL(k_emb, dim3(512), dim3(256), 0, stream, seq, emb, emb_b);
  hipLaunchKernelGGL(k_weff, dim3(32, 32), dim3(256), 0, stream, W_outp, W_inp, W_eff);
  hipLaunchKernelGGL(k_beff, dim3(2), dim3(256), 0, stream, W_outp, b_inp, b_outp, b_eff);

  // xprojT[j][t*32+b] = W_ih[:, :E] @ emb^T + (b_ih + b_hh) per-row
  hipLaunchKernelGGL(k_gemm, dim3(256), dim3(256), 0, stream,
                     wih_b, 1024, emb_b, 512, xprojT, 2048,
                     (const float*)nullptr, (const float*)nullptr, b_ih, b_hh, 512, 16);

  // persistent recurrence: all 64 steps, 2 fence-free flag-barriers each
  hipLaunchKernelGGL(k_recur, dim3(256), dim3(256), 0, stream,
                     xprojT, W_ih, W_hh, W_eff, b_eff, enc_c,
                     h_ext, outs_e, bar);

  hipLaunchKernelGGL(k_tr, dim3(512), dim3(256), 0, stream, outs_e + 16384, abt);
  // logits[b*T+t][V] = A_bt @ W_final^T + b_final
  hipLaunchKernelGGL(k_gemm, dim3(4000), dim3(256), 0, stream,
                     abt, 512, wfin_b, 512, logits, 32000,
                     b_final, (const float*)nullptr, (const float*)nullptr, (const float*)nullptr, 512, 16);
}